// Round 15
// baseline (341.871 us; speedup 1.0000x reference)
//
#include <hip/hip_runtime.h>
#include <hip/hip_bf16.h>

// ON-LSTM cell fused, R15: R11's best schedule (154us) + A-pack FUSED into
// the main kernel: A(t+1) is read as f32 from x/hx (coalesced f32x4,
// global->reg at p0), converted to bf16 and ds_write'd to swizzled LDS at
// p2/p3. pack_A kernel deleted (pack is W-only now). The cvt's compiler
// vmcnt waits at p2 retire all OLDER vmem ops (incl. the B-stage
// global_load_lds), so no manual vmcnt is needed anywhere in the loop.
//   p0: LDB(Bc) 8rd; LDA(q0)->afE 4rd; LDA(q1)->afO 4rd; ALOAD(t+1) 8xf32x4;
//       MF0(afE); BAR    <- BAR proves all waves' LDB done -> Bc restage ok
//   p1: LDA(q2)->afE; stage B(t+2)h0 (gload_lds x2); MF1(afO)
//   p2: LDA(q3)->afO; stage B(t+2)h1; AWRITE av[0..3]->An; MF2(afE)
//   p3: AWRITE av[4..7]->An; MF3(afO); lgkm0; BAR
// Race audit:
//  - An ds_writes @p2/p3: An held A(t-1), whose LDA reads drained by
//    t-1.p3's lgkm0+BAR. t+1.p0 LDA(An): this tile's p3 lgkm0 drains the
//    writes, BAR publishes. OK.
//  - Bc restage @p1/p2: p0's MF0 consumed every bfr value -> operand waits
//    retired all LDB reads; p0-end BAR publishes. OK.
//  - B(t+1) gloads (issued t-1.p1/p2) and B(t+2) gloads (t.p1/p2): each is
//    OLDER than t resp. t+1's av loads; the av-consuming cvts force
//    compiler vmcnt waits that retire them; following BAR publishes before
//    the consuming LDB at t+1 resp. t+2 .p0. OK.
//  - Tail T=31: ALOAD(0)/AWRITE + B stage wrap to valid-but-unused data. OK.

#define B_ROWS 8192
#define IN_DIM 1024
#define H_DIM  1024
#define NCHUNK 16
#define K_TOT  2048

#define BM   256
#define BN   256
#define BK   64
#define NKT  (K_TOT / BK)   // 32 K-tiles
#define THREADS 512

typedef __attribute__((ext_vector_type(4))) float  f32x4;
typedef __bf16 bf16x4 __attribute__((ext_vector_type(4)));
typedef __bf16 bf16x8 __attribute__((ext_vector_type(8)));

__device__ __forceinline__ float sigmoidf_(float x) {
    return 1.0f / (1.0f + __expf(-x));
}
__device__ __forceinline__ float tanhf_(float x) {
    float e = __expf(-2.0f * fabsf(x));
    float t = (1.0f - e) / (1.0f + e);
    return copysignf(t, x);
}

__device__ __forceinline__ void gload16(const __bf16* gsrc, __bf16* lds_dst) {
    __builtin_amdgcn_global_load_lds(
        (const __attribute__((address_space(1))) unsigned int*)gsrc,
        (__attribute__((address_space(3))) unsigned int*)lds_dst, 16, 0, 0);
}

__device__ __forceinline__ bf16x8 cvt8(f32x4 v0, f32x4 v1) {
    bf16x8 o;
    o[0] = (__bf16)v0.x; o[1] = (__bf16)v0.y; o[2] = (__bf16)v0.z; o[3] = (__bf16)v0.w;
    o[4] = (__bf16)v1.x; o[5] = (__bf16)v1.y; o[6] = (__bf16)v1.z; o[7] = (__bf16)v1.w;
    return o;
}

// ---- pack W only: Wp[bh=16][n=256][2048], gate-interleaved cols ----
__global__ __launch_bounds__(256)
void pack_W(const float* __restrict__ W_ih, const float* __restrict__ W_hh,
            __bf16* __restrict__ Wp)
{
    const int r  = blockIdx.x;            // 0..4095
    const int c8 = threadIdx.x << 3;
    const int bh = r >> 8;
    const int n  = r & 255;
    const int g  = (n >> 4) & 3;
    const int j  = (n >> 6) * 16 + (n & 15);
    const int wr = g * H_DIM + bh * 64 + j;
    const float* src = (c8 < IN_DIM)
        ? (W_ih + (size_t)wr * IN_DIM + c8)
        : (W_hh + (size_t)wr * IN_DIM + (c8 - IN_DIM));
    f32x4 v0 = *reinterpret_cast<const f32x4*>(src);
    f32x4 v1 = *reinterpret_cast<const f32x4*>(src + 4);
    *reinterpret_cast<bf16x8*>(Wp + (size_t)r * K_TOT + c8) = cvt8(v0, v1);
}

// stage one 128x64 B half-tile via global_load_lds (pre-swizzled source).
__device__ __forceinline__ void stage_half(const __bf16* __restrict__ gbase, int kb,
                                           __bf16* lbase, int row0, int tid) {
    #pragma unroll
    for (int i = 0; i < 2; ++i) {
        int e   = i * 4096 + tid * 8;
        int row = row0 + (e >> 6);
        int kd  = e & 63;
        gload16(gbase + (size_t)row * K_TOT + kb + (kd ^ ((row & 7) << 3)), lbase + e);
    }
}

#define SWZ(r, k) ((r) * 64 + ((k) ^ (((r) & 7) << 3)))

#define LDB(Bs) { \
    _Pragma("unroll") \
    for (int fn = 0; fn < 4; ++fn) { \
        int br = wcol + fn * 16 + lr; \
        bfr[fn][0] = *reinterpret_cast<const bf16x8*>(&(Bs)[SWZ(br, lh * 8)]); \
        bfr[fn][1] = *reinterpret_cast<const bf16x8*>(&(Bs)[SWZ(br, 32 + lh * 8)]); \
    } }

#define LDA_TO(dst, As, q) { \
    int ar = wrow + (q) * 32 + lr; \
    dst[0][0] = *reinterpret_cast<const bf16x8*>(&(As)[SWZ(ar, lh * 8)]); \
    dst[0][1] = *reinterpret_cast<const bf16x8*>(&(As)[SWZ(ar, 32 + lh * 8)]); \
    dst[1][0] = *reinterpret_cast<const bf16x8*>(&(As)[SWZ(ar + 16, lh * 8)]); \
    dst[1][1] = *reinterpret_cast<const bf16x8*>(&(As)[SWZ(ar + 16, 32 + lh * 8)]); \
    }

// A(t+1) f32 tile load: 8 coalesced f32x4/thread (lane-contiguous per j).
// e = j*2048 + tid*4 covers 16384 f32 = 256 rows x 64 cols.
#define ALOAD(T1) { \
    const int tt_ = (T1) & 31; \
    const float* As_ = (tt_ < 16) ? (xg + tt_ * BK) : (hxg + (tt_ * BK - IN_DIM)); \
    _Pragma("unroll") \
    for (int j = 0; j < 8; ++j) { \
        int e = j * 2048 + tid * 4; \
        av[j] = *reinterpret_cast<const f32x4*>( \
            As_ + (size_t)(bm * BM + (e >> 6)) * IN_DIM + (e & 63)); \
    } }

// convert av[j0..j0+3] and ds_write_b64 into swizzled LDS slots of An.
#define AWRITE(An, j0) { \
    _Pragma("unroll") \
    for (int j = (j0); j < (j0) + 4; ++j) { \
        int e = j * 2048 + tid * 4; \
        int row = e >> 6; int kd = e & 63; \
        bf16x4 s4; \
        s4[0] = (__bf16)av[j].x; s4[1] = (__bf16)av[j].y; \
        s4[2] = (__bf16)av[j].z; s4[3] = (__bf16)av[j].w; \
        *reinterpret_cast<bf16x4*>(&(An)[SWZ(row, kd)]) = s4; \
    } }

#define BARRIER do { \
    asm volatile("" ::: "memory"); \
    __builtin_amdgcn_s_barrier(); \
    asm volatile("" ::: "memory"); \
} while (0)
#define LGKM0 asm volatile("s_waitcnt lgkmcnt(0)" ::: "memory")

// 16 MFMAs for quadrant q from A-fragment set a (B frags fixed in bfr).
#define MF_Q(q, a) { \
    __builtin_amdgcn_s_setprio(1); \
    _Pragma("unroll") \
    for (int ks = 0; ks < 2; ++ks) { \
        _Pragma("unroll") \
        for (int fn = 0; fn < 4; ++fn) { \
            acc[2*(q)][fn]   = __builtin_amdgcn_mfma_f32_16x16x32_bf16(a[0][ks], bfr[fn][ks], acc[2*(q)][fn],   0,0,0); \
            acc[2*(q)+1][fn] = __builtin_amdgcn_mfma_f32_16x16x32_bf16(a[1][ks], bfr[fn][ks], acc[2*(q)+1][fn], 0,0,0); \
        } \
    } \
    __builtin_amdgcn_s_setprio(0); \
}

// one K-tile: Ac/An = A cur/next LDS buffers; Bc = B buffer for tile T.
#define TILE15(T, Ac, An, Bc) { \
    const int t_ = (T); \
    /* p0 */ \
    LDB(Bc); \
    LDA_TO(afE, Ac, 0); \
    LDA_TO(afO, Ac, 1); \
    ALOAD(t_ + 1); \
    MF_Q(0, afE); \
    BARRIER; \
    /* p1 */ \
    LDA_TO(afE, Ac, 2); \
    stage_half(Wblk, ((t_ + 2) & 31) * BK, Bc,        0,   tid); \
    MF_Q(1, afO); \
    /* p2 */ \
    LDA_TO(afO, Ac, 3); \
    stage_half(Wblk, ((t_ + 2) & 31) * BK, Bc + 8192, 128, tid); \
    AWRITE(An, 0); \
    MF_Q(2, afE); \
    /* p3 */ \
    AWRITE(An, 4); \
    MF_Q(3, afO); \
    LGKM0; \
    BARRIER; \
}

__global__ __launch_bounds__(THREADS, 2)
void onlstm_gemm15(const float* __restrict__ xg, const float* __restrict__ hxg,
                   const __bf16* __restrict__ Wp,
                   const float* __restrict__ cx,
                   const float* __restrict__ input_floor,
                   const float* __restrict__ forget_floor,
                   const float* __restrict__ b_ih, const float* __restrict__ b_hh,
                   float* __restrict__ out)
{
    __shared__ __align__(16) __bf16 lds[65536];          // 128 KiB: A0 A1 B0 B1
    __shared__ float ci_s[BM], cf_s[BM], bias_s[BN];

    const int tid = threadIdx.x;
    // XCD swizzle: xcd = n0&7 owns bm in [4*xcd, 4*xcd+4) x all 16 bh
    const int n0  = blockIdx.x;
    const int bm  = (n0 & 7) * 4 + ((n0 >> 3) & 3);   // 0..31
    const int bh  = n0 >> 5;                          // 0..15
    const int h0  = bh * 64;
    const int nc  = bh;

    // ---- prologue: bias + per-row cumulative-softmax master gates ----
    if (tid < BM) {
        {
            int g = (tid >> 4) & 3;
            int j = (tid >> 6) * 16 + (tid & 15);
            int wrr = g * H_DIM + h0 + j;
            bias_s[tid] = b_ih[wrr] + b_hh[wrr];
        }
        int b = bm * BM + tid;
        const int off = (nc < 8) ? 0 : 8;
        const int ic  = (nc < 8) ? nc : (nc - 8);
        const float* pin = input_floor  + (size_t)b * NCHUNK + off;
        const float* pfg = forget_floor + (size_t)b * NCHUNK + off;
        float vi[8], vf[8];
        float mi = -1e30f, mf = -1e30f;
        #pragma unroll
        for (int t = 0; t < 8; ++t) {
            vi[t] = pin[t]; vf[t] = pfg[t];
            mi = fmaxf(mi, vi[t]); mf = fmaxf(mf, vf[t]);
        }
        float si = 0.f, sf = 0.f;
        #pragma unroll
        for (int t = 0; t < 8; ++t) {
            vi[t] = __expf(vi[t] - mi); vf[t] = __expf(vf[t] - mf);
            si += vi[t]; sf += vf[t];
        }
        float pi = 0.f, pf = 0.f;
        #pragma unroll
        for (int t = 0; t < 8; ++t) { if (t <= ic) { pi += vi[t]; pf += vf[t]; } }
        float suf_i = si - pi + vi[ic];
        float suf_f = sf - pf + vf[ic];
        float civ, cfv;
        if (nc < 8) { civ = pi / si;    cfv = suf_f / sf; }
        else        { civ = suf_i / si; cfv = pf / sf;    }
        ci_s[tid] = civ; cf_s[tid] = cfv;
    }

    const __bf16* Wblk = Wp + (size_t)bh * 256 * K_TOT;
    __bf16* const A0p = lds;
    __bf16* const A1p = lds + 16384;
    __bf16* const B0p = lds + 32768;
    __bf16* const B1p = lds + 49152;

    const int l    = tid & 63;
    const int wid  = tid >> 6;        // 0..7
    const int wrw  = wid >> 2;        // 0..1  (M)
    const int wc   = wid & 3;         // 0..3  (N)
    const int lr   = l & 15;
    const int lh   = l >> 4;
    const int wrow = wrw * 128;
    const int wcol = wc * 64;

    f32x4 av[8];

    // prologue: stage B(0)->B0, B(1)->B1 (gload_lds); A(0)->A0 via f32+cvt
    stage_half(Wblk, 0,  B0p,        0,   tid);
    stage_half(Wblk, 0,  B0p + 8192, 128, tid);
    stage_half(Wblk, BK, B1p,        0,   tid);
    stage_half(Wblk, BK, B1p + 8192, 128, tid);
    ALOAD(0);
    AWRITE(A0p, 0);
    AWRITE(A0p, 4);
    LGKM0;                                                // ci/bias + A0 ds_writes done
    asm volatile("s_waitcnt vmcnt(4)" ::: "memory");      // B(0) resident; B(1) in flight
    __builtin_amdgcn_s_barrier();
    asm volatile("" ::: "memory");

    f32x4  acc[8][4];
    #pragma unroll
    for (int i = 0; i < 8; ++i)
        #pragma unroll
        for (int j = 0; j < 4; ++j) acc[i][j] = (f32x4){0.f, 0.f, 0.f, 0.f};
    bf16x8 afE[2][2], afO[2][2];
    bf16x8 bfr[4][2];

    #pragma unroll 1
    for (int it = 0; it < NKT / 2; ++it) {
        const int t = 2 * it;
        TILE15(t,     A0p, A1p, B0p);
        TILE15(t + 1, A1p, A0p, B1p);
    }
    asm volatile("s_waitcnt vmcnt(0) lgkmcnt(0)" ::: "memory");

    // ---- epilogue: all 4 gates of (b,h) lane-local (fn = gate) ----
    const size_t CY_OFF = (size_t)B_ROWS * H_DIM;
    const int hcol = h0 + wc * 16 + lr;
    #pragma unroll
    for (int m = 0; m < 8; ++m) {
        #pragma unroll
        for (int r = 0; r < 4; ++r) {
            int rt = wrow + m * 16 + lh * 4 + r;
            int b  = bm * BM + rt;
            float civ = ci_s[rt], cfv = cf_s[rt];
            float ovl = cfv * civ;
            float og = acc[m][0][r] + bias_s[wcol + lr];
            float cg = acc[m][1][r] + bias_s[wcol + 16 + lr];
            float ig = acc[m][2][r] + bias_s[wcol + 32 + lr];
            float fg = acc[m][3][r] + bias_s[wcol + 48 + lr];
            float i_s = sigmoidf_(ig);
            float f_s = sigmoidf_(fg);
            float c_t = tanhf_(cg);
            float o_s = sigmoidf_(og);
            float fq = f_s * ovl + (cfv - ovl);
            float iq = i_s * ovl + (civ - ovl);
            float cxv = cx[(size_t)b * H_DIM + hcol];
            float cyv = fq * cxv + iq * c_t;
            float hyv = o_s * tanhf_(cyv);
            out[(size_t)b * H_DIM + hcol] = hyv;
            out[CY_OFF + (size_t)b * H_DIM + hcol] = cyv;
        }
    }
}

extern "C" void kernel_launch(void* const* d_in, const int* in_sizes, int n_in,
                              void* d_out, int out_size, void* d_ws, size_t ws_size,
                              hipStream_t stream) {
    const float* x            = (const float*)d_in[0];
    const float* hx           = (const float*)d_in[1];
    const float* cx           = (const float*)d_in[2];
    const float* input_floor  = (const float*)d_in[3];
    const float* forget_floor = (const float*)d_in[4];
    const float* W_ih         = (const float*)d_in[5];
    const float* b_ih         = (const float*)d_in[6];
    const float* W_hh         = (const float*)d_in[7];
    const float* b_hh         = (const float*)d_in[8];
    float* out = (float*)d_out;

    __bf16* Wp = (__bf16*)d_ws;
    pack_W<<<16 * 256, 256, 0, stream>>>(W_ih, W_hh, Wp);
    onlstm_gemm15<<<512, THREADS, 0, stream>>>(
        x, hx, Wp, cx, input_floor, forget_floor, b_ih, b_hh, out);
}

// Round 16
// 193.693 us; speedup vs baseline: 1.7650x; 1.7650x over previous
//
#include <hip/hip_runtime.h>
#include <hip/hip_bf16.h>

// ON-LSTM cell fused, R16: co-residency + pipelining. Tile 128x256, BK=32,
// 8 waves (2Mx4N, 64x64/wave, acc=64 regs), LDS 48KB (A dbuf 2x8K, B dbuf
// 2x16K) + VGPR<=128 (__launch_bounds__(512,4)) -> 2 blocks/CU with
// independent barrier domains AND 4 waves/SIMD, running R11's pipelined
// schedule. R13 proved co-residency absorbs drains (full-drain cost only
// +3.5us); R11 proved the pipeline; this combines them.
// Per K-tile (BK=32):
//   p0: LDB(Bc) 4rd; LDA(m0) 1rd; stage A(t+1) (1 gload) -> An; MF(m0); BAR
//       (BAR after MF(m0)? MF(m0) consumes ALL bfr -> LDB retired -> but B
//        restage happens at p1/p2 into Bc of t+2... see audit)
//   p1: LDA(m1); stage B(t+2) op1 -> Bc; MF(m1)
//   p2: LDA(m2); stage B(t+2) op2 -> Bc; MF(m2)
//   p3: LDA(m3); MF(m3); lgkm0; vmcnt(2); BAR
// Race audit:
//  - Bc restage @p1/p2 (Bc holds B(t), dbuf alternates t/t+1): p0's MF(m0)
//    consumed every bfr frag -> operand waits retired all LDB(Bc) reads;
//    p0-end BAR publishes. Safe.
//  - An stage @p0: An held A(t-1); its last LDA read was t-1.p3, drained by
//    t-1.p3's lgkm0+BAR. Safe.
//  - t+1.p0 reads A(t+1)/B(t+1): vmcnt ledger at t.p3: outstanding =
//    B(t+1):2 [t-1.p1,p2] + A(t+1):1 [t.p0] + B(t+2):2 [t.p1,p2] = 5;
//    vmcnt(2) drains the 3 oldest = B(t+1)+A(t+1); BAR publishes. Safe.
//  - Tail t=62,63: stages wrap (t+1)&63/(t+2)&63 -> valid unused memory. OK.

#define B_ROWS 8192
#define IN_DIM 1024
#define H_DIM  1024
#define NCHUNK 16
#define K_TOT  2048

#define BM   128
#define BN   256
#define BK   32
#define NKT  (K_TOT / BK)   // 64 K-tiles
#define THREADS 512

#define A_PACK_BYTES ((size_t)B_ROWS * K_TOT * 2)        // 32 MiB
#define W_PACK_BYTES ((size_t)16 * 256 * K_TOT * 2)      // 16 MiB

typedef __attribute__((ext_vector_type(4))) float  f32x4;
typedef __bf16 bf16x8 __attribute__((ext_vector_type(8)));

__device__ __forceinline__ float sigmoidf_(float x) {
    return 1.0f / (1.0f + __expf(-x));
}
__device__ __forceinline__ float tanhf_(float x) {
    float e = __expf(-2.0f * fabsf(x));
    float t = (1.0f - e) / (1.0f + e);
    return copysignf(t, x);
}

__device__ __forceinline__ void gload16(const __bf16* gsrc, __bf16* lds_dst) {
    __builtin_amdgcn_global_load_lds(
        (const __attribute__((address_space(1))) unsigned int*)gsrc,
        (__attribute__((address_space(3))) unsigned int*)lds_dst, 16, 0, 0);
}

__device__ __forceinline__ bf16x8 cvt8(f32x4 v0, f32x4 v1) {
    bf16x8 o;
    o[0] = (__bf16)v0.x; o[1] = (__bf16)v0.y; o[2] = (__bf16)v0.z; o[3] = (__bf16)v0.w;
    o[4] = (__bf16)v1.x; o[5] = (__bf16)v1.y; o[6] = (__bf16)v1.z; o[7] = (__bf16)v1.w;
    return o;
}

// ---- fused pack: blocks [0,8192) pack A rows; [8192,12288) pack W rows ----
// Wp[bh=16][n=256][2048]; col n: gate g=(n>>4)&3, h j=(n>>6)*16+(n&15).
__global__ __launch_bounds__(256)
void pack_AW(const float* __restrict__ x, const float* __restrict__ hx,
             const float* __restrict__ W_ih, const float* __restrict__ W_hh,
             __bf16* __restrict__ Abf, __bf16* __restrict__ Wp)
{
    const int bid = blockIdx.x;
    const int c8  = threadIdx.x << 3;
    if (bid < B_ROWS) {
        const float* src = (c8 < IN_DIM)
            ? (x  + (size_t)bid * IN_DIM + c8)
            : (hx + (size_t)bid * IN_DIM + (c8 - IN_DIM));
        f32x4 v0 = *reinterpret_cast<const f32x4*>(src);
        f32x4 v1 = *reinterpret_cast<const f32x4*>(src + 4);
        *reinterpret_cast<bf16x8*>(Abf + (size_t)bid * K_TOT + c8) = cvt8(v0, v1);
    } else {
        const int r  = bid - B_ROWS;       // 0..4095
        const int bh = r >> 8;
        const int n  = r & 255;
        const int g  = (n >> 4) & 3;
        const int j  = (n >> 6) * 16 + (n & 15);
        const int wr = g * H_DIM + bh * 64 + j;
        const float* src = (c8 < IN_DIM)
            ? (W_ih + (size_t)wr * IN_DIM + c8)
            : (W_hh + (size_t)wr * IN_DIM + (c8 - IN_DIM));
        f32x4 v0 = *reinterpret_cast<const f32x4*>(src);
        f32x4 v1 = *reinterpret_cast<const f32x4*>(src + 4);
        *reinterpret_cast<bf16x8*>(Wp + (size_t)r * K_TOT + c8) = cvt8(v0, v1);
    }
}

// stage one 128x32 slab (512 thr x 16B = 8 KB): linear LDS dest,
// inverse-swizzled global source (BK=32 swizzle: k ^= (row&3)<<3).
__device__ __forceinline__ void stage_s(const __bf16* __restrict__ gbase, int kb,
                                        __bf16* lbase, int row0, int tid) {
    int e   = tid * 8;
    int row = row0 + (e >> 5);
    int kd  = e & 31;
    gload16(gbase + (size_t)row * K_TOT + kb + (kd ^ ((row & 3) << 3)), lbase + e);
}

#define SWZ32(r, k) ((r) * 32 + ((k) ^ (((r) & 3) << 3)))

#define LDB(Bs) { \
    _Pragma("unroll") \
    for (int fn = 0; fn < 4; ++fn) { \
        int br = wcol + fn * 16 + lr; \
        bfr[fn] = *reinterpret_cast<const bf16x8*>(&(Bs)[SWZ32(br, lh * 8)]); \
    } }

#define LDA(As, m) { \
    int ar = wrow + (m) * 16 + lr; \
    af = *reinterpret_cast<const bf16x8*>(&(As)[SWZ32(ar, lh * 8)]); \
    }

#define BARRIER do { \
    asm volatile("" ::: "memory"); \
    __builtin_amdgcn_s_barrier(); \
    asm volatile("" ::: "memory"); \
} while (0)
#define LGKM0 asm volatile("s_waitcnt lgkmcnt(0)" ::: "memory")

// 4 independent MFMAs: m-frag m x 4 n-frags (full K=32 per MFMA)
#define MF_M(m) { \
    __builtin_amdgcn_s_setprio(1); \
    _Pragma("unroll") \
    for (int fn = 0; fn < 4; ++fn) { \
        acc[m][fn] = __builtin_amdgcn_mfma_f32_16x16x32_bf16(af, bfr[fn], acc[m][fn], 0, 0, 0); \
    } \
    __builtin_amdgcn_s_setprio(0); \
}

// one K-tile: Ac/An = A cur/next; Bc = this tile's B buffer (restaged t+2)
#define TILE16(T, Ac, An, Bc) { \
    const int t_ = (T); \
    /* p0 */ \
    LDB(Bc); \
    LDA(Ac, 0); \
    stage_s(Arow, ((t_ + 1) & 63) * BK, An, 0, tid); \
    MF_M(0); \
    BARRIER; \
    /* p1 */ \
    LDA(Ac, 1); \
    stage_s(Wblk, ((t_ + 2) & 63) * BK, Bc,        0,   tid); \
    MF_M(1); \
    /* p2 */ \
    LDA(Ac, 2); \
    stage_s(Wblk, ((t_ + 2) & 63) * BK, Bc + 4096, 128, tid); \
    MF_M(2); \
    /* p3 */ \
    LDA(Ac, 3); \
    MF_M(3); \
    LGKM0; \
    asm volatile("s_waitcnt vmcnt(2)" ::: "memory"); \
    BARRIER; \
}

__global__ __launch_bounds__(THREADS, 4)
void onlstm_gemm16(const __bf16* __restrict__ Abf, const __bf16* __restrict__ Wp,
                   const float* __restrict__ cx,
                   const float* __restrict__ input_floor,
                   const float* __restrict__ forget_floor,
                   const float* __restrict__ b_ih, const float* __restrict__ b_hh,
                   float* __restrict__ out)
{
    __shared__ __align__(16) __bf16 lds[24576];   // A0 4K | A1 4K | B0 8K | B1 8K elems
    __shared__ float ci_s[BM], cf_s[BM], bias_s[BN];

    const int tid = threadIdx.x;
    // bijective XCD swizzle: 1024 blocks; xcd = n0&7 owns bm in [8*xcd,8*xcd+8)
    const int n0  = blockIdx.x;
    const int bm  = (n0 & 7) * 8 + ((n0 >> 3) & 7);   // 0..63
    const int bh  = n0 >> 6;                          // 0..15
    const int h0  = bh * 64;
    const int nc  = bh;

    // ---- prologue: bias + per-row cumulative-softmax master gates ----
    if (tid < BN) {
        int g = (tid >> 4) & 3;
        int j = (tid >> 6) * 16 + (tid & 15);
        int wrr = g * H_DIM + h0 + j;
        bias_s[tid] = b_ih[wrr] + b_hh[wrr];
    }
    if (tid < BM) {
        int b = bm * BM + tid;
        const int off = (nc < 8) ? 0 : 8;
        const int ic  = (nc < 8) ? nc : (nc - 8);
        const float* pin = input_floor  + (size_t)b * NCHUNK + off;
        const float* pfg = forget_floor + (size_t)b * NCHUNK + off;
        float vi[8], vf[8];
        float mi = -1e30f, mf = -1e30f;
        #pragma unroll
        for (int t = 0; t < 8; ++t) {
            vi[t] = pin[t]; vf[t] = pfg[t];
            mi = fmaxf(mi, vi[t]); mf = fmaxf(mf, vf[t]);
        }
        float si = 0.f, sf = 0.f;
        #pragma unroll
        for (int t = 0; t < 8; ++t) {
            vi[t] = __expf(vi[t] - mi); vf[t] = __expf(vf[t] - mf);
            si += vi[t]; sf += vf[t];
        }
        float pi = 0.f, pf = 0.f;
        #pragma unroll
        for (int t = 0; t < 8; ++t) { if (t <= ic) { pi += vi[t]; pf += vf[t]; } }
        float suf_i = si - pi + vi[ic];
        float suf_f = sf - pf + vf[ic];
        float civ, cfv;
        if (nc < 8) { civ = pi / si;    cfv = suf_f / sf; }
        else        { civ = suf_i / si; cfv = pf / sf;    }
        ci_s[tid] = civ; cf_s[tid] = cfv;
    }

    const __bf16* Arow = Abf + (size_t)(bm * BM) * K_TOT;
    const __bf16* Wblk = Wp  + (size_t)bh * 256 * K_TOT;
    __bf16* const A0p = lds;
    __bf16* const A1p = lds + 4096;
    __bf16* const B0p = lds + 8192;
    __bf16* const B1p = lds + 16384;

    const int l    = tid & 63;
    const int wid  = tid >> 6;        // 0..7
    const int wrw  = wid >> 2;        // 0..1  (M)
    const int wc   = wid & 3;         // 0..3  (N)
    const int lr   = l & 15;
    const int lh   = l >> 4;
    const int wrow = wrw * 64;
    const int wcol = wc * 64;

    // prologue staging: A(0)->A0 (1), B(0)->B0 (2), B(1)->B1 (2)
    stage_s(Arow, 0,  A0p,        0,   tid);
    stage_s(Wblk, 0,  B0p,        0,   tid);
    stage_s(Wblk, 0,  B0p + 4096, 128, tid);
    stage_s(Wblk, BK, B1p,        0,   tid);
    stage_s(Wblk, BK, B1p + 4096, 128, tid);
    LGKM0;                                                // ci/bias ds_writes done
    asm volatile("s_waitcnt vmcnt(2)" ::: "memory");      // A(0),B(0) done; B(1) in flight
    __builtin_amdgcn_s_barrier();
    asm volatile("" ::: "memory");

    f32x4  acc[4][4];
    #pragma unroll
    for (int i = 0; i < 4; ++i)
        #pragma unroll
        for (int j = 0; j < 4; ++j) acc[i][j] = (f32x4){0.f, 0.f, 0.f, 0.f};
    bf16x8 af;
    bf16x8 bfr[4];

    #pragma unroll 1
    for (int it = 0; it < NKT / 2; ++it) {
        const int t = 2 * it;
        TILE16(t,     A0p, A1p, B0p);
        TILE16(t + 1, A1p, A0p, B1p);
    }
    asm volatile("s_waitcnt vmcnt(0) lgkmcnt(0)" ::: "memory");

    // ---- epilogue: all 4 gates of (b,h) lane-local (fn = gate) ----
    const size_t CY_OFF = (size_t)B_ROWS * H_DIM;
    const int hcol = h0 + wc * 16 + lr;
    #pragma unroll
    for (int m = 0; m < 4; ++m) {
        #pragma unroll
        for (int r = 0; r < 4; ++r) {
            int rt = wrow + m * 16 + lh * 4 + r;
            int b  = bm * BM + rt;
            float civ = ci_s[rt], cfv = cf_s[rt];
            float ovl = cfv * civ;
            float og = acc[m][0][r] + bias_s[wcol + lr];
            float cg = acc[m][1][r] + bias_s[wcol + 16 + lr];
            float ig = acc[m][2][r] + bias_s[wcol + 32 + lr];
            float fg = acc[m][3][r] + bias_s[wcol + 48 + lr];
            float i_s = sigmoidf_(ig);
            float f_s = sigmoidf_(fg);
            float c_t = tanhf_(cg);
            float o_s = sigmoidf_(og);
            float fq = f_s * ovl + (cfv - ovl);
            float iq = i_s * ovl + (civ - ovl);
            float cxv = cx[(size_t)b * H_DIM + hcol];
            float cyv = fq * cxv + iq * c_t;
            float hyv = o_s * tanhf_(cyv);
            out[(size_t)b * H_DIM + hcol] = hyv;
            out[CY_OFF + (size_t)b * H_DIM + hcol] = cyv;
        }
    }
}

extern "C" void kernel_launch(void* const* d_in, const int* in_sizes, int n_in,
                              void* d_out, int out_size, void* d_ws, size_t ws_size,
                              hipStream_t stream) {
    const float* x            = (const float*)d_in[0];
    const float* hx           = (const float*)d_in[1];
    const float* cx           = (const float*)d_in[2];
    const float* input_floor  = (const float*)d_in[3];
    const float* forget_floor = (const float*)d_in[4];
    const float* W_ih         = (const float*)d_in[5];
    const float* b_ih         = (const float*)d_in[6];
    const float* W_hh         = (const float*)d_in[7];
    const float* b_hh         = (const float*)d_in[8];
    float* out = (float*)d_out;

    __bf16* Abf = (__bf16*)d_ws;
    __bf16* Wp  = (__bf16*)((char*)d_ws + A_PACK_BYTES);
    pack_AW<<<B_ROWS + 16 * 256, 256, 0, stream>>>(x, hx, W_ih, W_hh, Abf, Wp);
    onlstm_gemm16<<<1024, THREADS, 0, stream>>>(
        Abf, Wp, cx, input_floor, forget_floor, b_ih, b_hh, out);
}